// Round 10
// baseline (549.260 us; speedup 1.0000x reference)
//
#include <hip/hip_runtime.h>

#define TS 1000

__device__ __forceinline__ float rl(float v, int l) {
    return __int_as_float(__builtin_amdgcn_readlane(__float_as_int(v), l));
}
__device__ __forceinline__ float fsig(float x) {
    return __builtin_amdgcn_rcpf(1.0f + __expf(-x));
}
__device__ __forceinline__ float ftanh(float x) {
    return 1.0f - 2.0f * __builtin_amdgcn_rcpf(1.0f + __expf(2.0f * x));
}

// One block per (g,b) chain, 4 UNIFIED waves (1 per SIMD — no issue
// contention, no role straggler). Wave sw covers K-rows [16sw,16sw+16) of
// BOTH U (on h(t)) and W (on x(t+2)): 96 stationary weights/lane.
// One NON-draining s_barrier per step; x loads stay in flight across it.
// x pipeline: 8 register sets, depth 8, uniform s_waitcnt vmcnt(6):
//   at body t's wait the newest-6 VMEM ops are (worst case) 4 newest loads
//   x(t+5..t+8) + <=2 lingering stores  =>  x(t+4) and older retired
//   =>  x(t+2) (this body's operand) is guaranteed, with no wait on any
//   load younger than 4 bodies. Robust to store/load reordering.
// Ring audit (write pre-barrier, read post-barrier, >=1 barrier between
// any read and the next rewrite):
//   cpart[t&1]: W pre-b(t), R post-b(t), reW pre-b(t+2)  (barrier t+1 between)
//   ppart[s=t&3]: W pre-b(t-2), R post-b(t), reW pre-b(t+2) (barrier t+1)
// All 4 waves compute gates redundantly with identical fixed-order sums ->
// bitwise-identical h replicas -> deterministic across graph replays.
__global__ __launch_bounds__(256)
__attribute__((amdgpu_waves_per_eu(1, 1)))
void gru_uni4(const float* __restrict__ x, const float* __restrict__ h0,
              const float* __restrict__ W, const float* __restrict__ U,
              const float* __restrict__ bi, const float* __restrict__ bh,
              float* __restrict__ out, float* __restrict__ hout)
{
    __shared__ float4 cpart[2][4][64];   // U·h partials, slot = t & 1
    __shared__ float4 ppart[4][4][64];   // W·x partials, slot s holds gx(s mod 4)

    const int tid  = threadIdx.x;
    const int lane = tid & 63;
    const int sw   = tid >> 6;
    const int kb   = __builtin_amdgcn_readfirstlane(sw * 16);

    const int g = blockIdx.x >> 5, b = blockIdx.x & 31;

    // 96 stationary weights/lane: U rows kb..kb+15 and W rows kb..kb+15.
    float u0[16], u1[16], u2[16], v0[16], v1[16], v2[16];
    {
        const float* Ug = U + (size_t)g * (64 * 192) + (size_t)kb * 192 + lane;
        const float* Wg = W + (size_t)g * (64 * 192) + (size_t)kb * 192 + lane;
        #pragma unroll
        for (int k = 0; k < 16; ++k) {
            u0[k] = Ug[k * 192]; u1[k] = Ug[k * 192 + 64]; u2[k] = Ug[k * 192 + 128];
            v0[k] = Wg[k * 192]; v1[k] = Wg[k * 192 + 64]; v2[k] = Wg[k * 192 + 128];
        }
    }
    #pragma unroll
    for (int k = 0; k < 16; ++k) {
        asm volatile("" : "+v"(u0[k]), "+v"(u1[k]), "+v"(u2[k]));
        asm volatile("" : "+v"(v0[k]), "+v"(v1[k]), "+v"(v2[k]));
    }

    // b_h folded into sw0's U-acc init; b_i into sw0's W-acc init.
    float ubz = 0.f, ubr = 0.f, ubn = 0.f, wbz = 0.f, wbr = 0.f, wbn = 0.f;
    if (sw == 0) {
        ubz = bh[g * 192 + lane]; ubr = bh[g * 192 + 64 + lane]; ubn = bh[g * 192 + 128 + lane];
        wbz = bi[g * 192 + lane]; wbr = bi[g * 192 + 64 + lane]; wbn = bi[g * 192 + 128 + lane];
    }

    float h = h0[(g * 32 + b) * 64 + lane];    // replicated in all 4 waves

    const float* xp = x + (size_t)b * (TS * 512) + g * 64 + lane;
    float* op = out + (size_t)b * (TS * 512) + g * 64 + lane;

    // 8 x register sets, written ONLY by asm loads, statically indexed by the
    // 8x-unrolled t-loop: set (time & 7) holds x(time).
    float xs0 = 0.f, xs1 = 0.f, xs2 = 0.f, xs3 = 0.f;
    float xs4 = 0.f, xs5 = 0.f, xs6 = 0.f, xs7 = 0.f;

#define XLOAD(DST, T_)                                                        \
    { const float* pp_ = xp + (size_t)(T_) * 512;                             \
      asm volatile("global_load_dword %0, %1, off" : "=v"(DST) : "v"(pp_)); }

#define WPROD(XS, SLOT)                                                       \
    {                                                                         \
        float az = wbz, ar = wbr, an = wbn;                                   \
        float az2 = 0.f, ar2 = 0.f, an2 = 0.f;                                \
        _Pragma("unroll")                                                     \
        for (int k = 0; k < 8; ++k) {                                         \
            const float s = rl(XS, kb + k);                                   \
            az = fmaf(s, v0[k], az); ar = fmaf(s, v1[k], ar); an = fmaf(s, v2[k], an); \
        }                                                                     \
        _Pragma("unroll")                                                     \
        for (int k = 8; k < 16; ++k) {                                        \
            const float s = rl(XS, kb + k);                                   \
            az2 = fmaf(s, v0[k], az2); ar2 = fmaf(s, v1[k], ar2); an2 = fmaf(s, v2[k], an2); \
        }                                                                     \
        ppart[SLOT][sw][lane] = make_float4(az + az2, ar + ar2, an + an2, 0.f); \
    }

    // ---- prologue: x(0..7) in flight; gx(0)->slot0, gx(1)->slot1.
    XLOAD(xs0, 0) XLOAD(xs1, 1) XLOAD(xs2, 2) XLOAD(xs3, 3)
    XLOAD(xs4, 4) XLOAD(xs5, 5) XLOAD(xs6, 6) XLOAD(xs7, 7)
    asm volatile("s_waitcnt vmcnt(6)" : "+v"(xs0), "+v"(xs1));
    WPROD(xs0, 0)
    WPROD(xs1, 1)
    asm volatile("s_waitcnt lgkmcnt(0)" ::: "memory");
    __builtin_amdgcn_s_barrier();

#define BODY(J, XS_USE, XS_FILL)                                              \
    {                                                                         \
        const int t = tt + (J);                                               \
        int tl = t + 8; if (tl > TS - 1) tl = TS - 1;                         \
        XLOAD(XS_FILL, tl)                                                    \
        asm volatile("s_waitcnt vmcnt(6)" : "+v"(XS_USE));                    \
        /* U·h(t) partial */                                                  \
        {                                                                     \
            float az = ubz, ar = ubr, an = ubn;                               \
            float az2 = 0.f, ar2 = 0.f, an2 = 0.f;                            \
            _Pragma("unroll")                                                 \
            for (int k = 0; k < 8; ++k) {                                     \
                const float s = rl(h, kb + k);                                \
                az = fmaf(s, u0[k], az); ar = fmaf(s, u1[k], ar); an = fmaf(s, u2[k], an); \
            }                                                                 \
            _Pragma("unroll")                                                 \
            for (int k = 8; k < 16; ++k) {                                    \
                const float s = rl(h, kb + k);                                \
                az2 = fmaf(s, u0[k], az2); ar2 = fmaf(s, u1[k], ar2); an2 = fmaf(s, u2[k], an2); \
            }                                                                 \
            cpart[(J) & 1][sw][lane] = make_float4(az + az2, ar + ar2, an + an2, 0.f); \
        }                                                                     \
        /* W·x(t+2) partial -> slot (t+2)&3 */                                \
        WPROD(XS_USE, (J + 2) & 3)                                            \
        asm volatile("s_waitcnt lgkmcnt(0)" ::: "memory");                    \
        __builtin_amdgcn_sched_barrier(0);                                    \
        __builtin_amdgcn_s_barrier();          /* NO vmcnt drain */           \
        __builtin_amdgcn_sched_barrier(0);                                    \
        {                                                                     \
            const float4 c0 = cpart[(J) & 1][0][lane];                        \
            const float4 c1 = cpart[(J) & 1][1][lane];                        \
            const float4 c2 = cpart[(J) & 1][2][lane];                        \
            const float4 c3 = cpart[(J) & 1][3][lane];                        \
            const float4 q0 = ppart[(J) & 3][0][lane];                        \
            const float4 q1 = ppart[(J) & 3][1][lane];                        \
            const float4 q2 = ppart[(J) & 3][2][lane];                        \
            const float4 q3 = ppart[(J) & 3][3][lane];                        \
            const float ghz = ((c0.x + c1.x) + c2.x) + c3.x;                  \
            const float ghr = ((c0.y + c1.y) + c2.y) + c3.y;                  \
            const float ghn = ((c0.z + c1.z) + c2.z) + c3.z;                  \
            const float gxz = ((q0.x + q1.x) + q2.x) + q3.x;                  \
            const float gxr = ((q0.y + q1.y) + q2.y) + q3.y;                  \
            const float gxn = ((q0.z + q1.z) + q2.z) + q3.z;                  \
            const float z = fsig(gxz + ghz);                                  \
            const float r = fsig(gxr + ghr);                                  \
            const float n = ftanh(fmaf(r, ghn, gxn));   /* reset_after */     \
            h = n + z * (h - n);                                              \
            if (sw == 0) op[(size_t)t * 512] = h;                             \
        }                                                                     \
    }

    for (int tt = 0; tt < TS; tt += 8) {
        BODY(0, xs2, xs0)
        BODY(1, xs3, xs1)
        BODY(2, xs4, xs2)
        BODY(3, xs5, xs3)
        BODY(4, xs6, xs4)
        BODY(5, xs7, xs5)
        BODY(6, xs0, xs6)
        BODY(7, xs1, xs7)
    }
#undef BODY
#undef WPROD
#undef XLOAD

    if (sw == 0)
        hout[(g * 32 + b) * 64 + lane] = h;
}

extern "C" void kernel_launch(void* const* d_in, const int* in_sizes, int n_in,
                              void* d_out, int out_size, void* d_ws, size_t ws_size,
                              hipStream_t stream) {
    const float* x  = (const float*)d_in[0];
    const float* h0 = (const float*)d_in[1];
    const float* W  = (const float*)d_in[2];
    const float* U  = (const float*)d_in[3];
    const float* bi = (const float*)d_in[4];
    const float* bh = (const float*)d_in[5];
    float* out  = (float*)d_out;
    float* hout = out + (size_t)32 * TS * 512;
    hipLaunchKernelGGL(gru_uni4, dim3(256), dim3(256), 0, stream,
                       x, h0, W, U, bi, bh, out, hout);
}

// Round 11
// 494.652 us; speedup vs baseline: 1.1104x; 1.1104x over previous
//
#include <hip/hip_runtime.h>

#define TS 1000

__device__ __forceinline__ float rl(float v, int l) {
    return __int_as_float(__builtin_amdgcn_readlane(__float_as_int(v), l));
}
__device__ __forceinline__ float fsig(float x) {
    return __builtin_amdgcn_rcpf(1.0f + __expf(-x));
}
__device__ __forceinline__ float ftanh(float x) {
    return 1.0f - 2.0f * __builtin_amdgcn_rcpf(1.0f + __expf(2.0f * x));
}

// Round-8 structure (best: 518 us kernel) + ONE change: the consumer's psum
// read moves PRE-barrier (psum[t&3] is stable since barrier(t-1)), shrinking
// the post-barrier serial path to 4 cpart reads + adds + gates.
//
// One block per (g,b) chain, 8 waves (2/SIMD):
//   wid 0-3 = consumers: U·h(t) partials, K-split 16.
//   wid 4-7 = producers: W·x(t+2) partials, K-split 16, x prefetched deep
//             via inline-asm global_load + tied s_waitcnt vmcnt(2).
//   producer sw0 PRE-REDUCES the 4 gx partials of step t+1 into psum[(t+1)&3].
// One NON-draining s_barrier per step; x loads stay in flight across it.
// Ring audit (write pre-barrier, read barrier-separated, >=2 barriers
// between last read and rewrite):
//   cpart[t&1]: write pre-b(t), read post-b(t), rewrite pre-b(t+2).
//   ppart[s=(t+2)&3]: write pre-b(t), reducer-read pre-b(t+1), rewrite pre-b(t+4).
//   psum[s=t&3]: write pre-b(t-1), consumer-read pre-b(t) (b(t-1) between),
//                rewrite pre-b(t+3) (b(t),b(t+1),b(t+2) between).
// All 4 consumer waves compute gates redundantly with identical fixed-order
// sums -> bitwise-identical h replicas -> deterministic across replays.
__global__ __launch_bounds__(512)
__attribute__((amdgpu_waves_per_eu(2, 2)))
void gru_fused8(const float* __restrict__ x, const float* __restrict__ h0,
                const float* __restrict__ W, const float* __restrict__ U,
                const float* __restrict__ bi, const float* __restrict__ bh,
                float* __restrict__ out, float* __restrict__ hout)
{
    __shared__ float4 cpart[2][4][64];   // consumer partials, slot = t & 1
    __shared__ float4 ppart[4][4][64];   // producer partials, slot s holds gx(s mod)
    __shared__ float4 psum[4][64];       // pre-reduced gx, slot = t & 3

    const int tid  = threadIdx.x;
    const int lane = tid & 63;
    const int wid  = tid >> 6;
    const int role = wid >> 2;               // 0 = consumer, 1 = producer
    const int sw   = wid & 3;                // K-split index within role
    const int kb   = __builtin_amdgcn_readfirstlane(sw * 16);

    const int g = blockIdx.x >> 5, b = blockIdx.x & 31;

    // 48 stationary weights/lane: k-rows kb..kb+15, 3 gate columns.
    float w0[16], w1[16], w2[16];
    {
        const float* P = ((role == 0) ? U : W) + (size_t)g * (64 * 192) + (size_t)kb * 192 + lane;
        #pragma unroll
        for (int k = 0; k < 16; ++k) {
            w0[k] = P[k * 192];
            w1[k] = P[k * 192 + 64];
            w2[k] = P[k * 192 + 128];
        }
    }
    #pragma unroll
    for (int k = 0; k < 16; ++k)
        asm volatile("" : "+v"(w0[k]), "+v"(w1[k]), "+v"(w2[k]));

    // b_h folded into consumer sw0; b_i folded into producer sw0.
    float bz = 0.f, br = 0.f, bn = 0.f;
    if (sw == 0) {
        const float* bb = ((role == 0) ? bh : bi) + g * 192 + lane;
        bz = bb[0]; br = bb[64]; bn = bb[128];
    }

    float h = 0.f;
    if (role == 0) h = h0[(g * 32 + b) * 64 + lane];   // replicated, 4 consumer waves

    const float* xp = x + (size_t)b * (TS * 512) + g * 64 + lane;
    float* op = out + (size_t)b * (TS * 512) + g * 64 + lane;

    // Producer x register sets, written ONLY by asm loads, statically indexed
    // via the 4x-unrolled t-loop: set (time & 3) holds x(time).
    float xs0 = 0.f, xs1 = 0.f, xs2 = 0.f, xs3 = 0.f;

#define XLOAD(DST, T_)                                                        \
    { const float* pp_ = xp + (size_t)(T_) * 512;                             \
      asm volatile("global_load_dword %0, %1, off" : "=v"(DST) : "v"(pp_)); }

#define PPROD(XS, SLOT)                                                       \
    {                                                                         \
        float az = bz, ar = br, an = bn;                                      \
        _Pragma("unroll")                                                     \
        for (int k = 0; k < 16; ++k) {                                        \
            const float s = rl(XS, kb + k);                                   \
            az = fmaf(s, w0[k], az);                                          \
            ar = fmaf(s, w1[k], ar);                                          \
            an = fmaf(s, w2[k], an);                                          \
        }                                                                     \
        ppart[SLOT][sw][lane] = make_float4(az, ar, an, 0.f);                 \
    }

#define PREDUCE(SLOT)                                                         \
    {                                                                         \
        const float4 q0 = ppart[SLOT][0][lane];                               \
        const float4 q1 = ppart[SLOT][1][lane];                               \
        const float4 q2 = ppart[SLOT][2][lane];                               \
        const float4 q3 = ppart[SLOT][3][lane];                               \
        psum[SLOT][lane] = make_float4(((q0.x + q1.x) + q2.x) + q3.x,         \
                                       ((q0.y + q1.y) + q2.y) + q3.y,         \
                                       ((q0.z + q1.z) + q2.z) + q3.z, 0.f);   \
    }

    // ---- producer prologue: gx(0)->ppart[0], gx(1)->ppart[1]; x(2),x(3) in flight.
    if (role == 1) {
        XLOAD(xs0, 0) XLOAD(xs1, 1) XLOAD(xs2, 2) XLOAD(xs3, 3)
        asm volatile("s_waitcnt vmcnt(2)" : "+v"(xs0), "+v"(xs1));
        PPROD(xs0, 0)
        PPROD(xs1, 1)
    }
    asm volatile("s_waitcnt lgkmcnt(0)" ::: "memory");
    __builtin_amdgcn_s_barrier();
    // psum[0] must be ready BEFORE body 0's pre-barrier read -> own barrier.
    if (role == 1 && sw == 0) PREDUCE(0)
    asm volatile("s_waitcnt lgkmcnt(0)" ::: "memory");
    __builtin_amdgcn_s_barrier();

#define BODY(J, XS_USE, XS_FILL)                                              \
    {                                                                         \
        const int t = tt + (J);                                               \
        float qx = 0.f, qy = 0.f, qz = 0.f;                                   \
        if (role == 1) {                                                      \
            /* issue x(t+4) into the set freed 2 bodies ago */                \
            int tl = t + 4; if (tl > TS - 1) tl = TS - 1;                     \
            XLOAD(XS_FILL, tl)                                                \
            /* x(t+2) guaranteed arrived: 3 outstanding -> wait to 2 */       \
            asm volatile("s_waitcnt vmcnt(2)" : "+v"(XS_USE));                \
            PPROD(XS_USE, (J + 2) & 3)                                        \
            if (sw == 0) PREDUCE((J + 1) & 3)   /* pre-reduce gx(t+1) */      \
        } else {                                                              \
            /* psum[t&3] stable since b(t-1): read EARLY, hide under fmas */  \
            const float4 q = psum[(J) & 3][lane];                             \
            float az = bz, ar = br, an = bn;                                  \
            _Pragma("unroll")                                                 \
            for (int k = 0; k < 16; ++k) {                                    \
                const float s = rl(h, kb + k);                                \
                az = fmaf(s, w0[k], az);                                      \
                ar = fmaf(s, w1[k], ar);                                      \
                an = fmaf(s, w2[k], an);                                      \
            }                                                                 \
            cpart[(J) & 1][sw][lane] = make_float4(az, ar, an, 0.f);          \
            qx = q.x; qy = q.y; qz = q.z;                                     \
        }                                                                     \
        asm volatile("s_waitcnt lgkmcnt(0)" ::: "memory");                    \
        __builtin_amdgcn_sched_barrier(0);                                    \
        __builtin_amdgcn_s_barrier();          /* NO vmcnt drain */           \
        __builtin_amdgcn_sched_barrier(0);                                    \
        if (role == 0) {                                                      \
            __builtin_amdgcn_s_setprio(1);     /* consumer = critical path */ \
            const float4 c0 = cpart[(J) & 1][0][lane];                        \
            const float4 c1 = cpart[(J) & 1][1][lane];                        \
            const float4 c2 = cpart[(J) & 1][2][lane];                        \
            const float4 c3 = cpart[(J) & 1][3][lane];                        \
            const float sz = (qx + (c0.x + c1.x)) + (c2.x + c3.x);            \
            const float sr = (qy + (c0.y + c1.y)) + (c2.y + c3.y);            \
            const float ghn = (c0.z + c1.z) + (c2.z + c3.z);                  \
            const float z = fsig(sz);                                         \
            const float r = fsig(sr);                                         \
            const float n = ftanh(fmaf(r, ghn, qz));    /* reset_after */     \
            h = n + z * (h - n);                                              \
            __builtin_amdgcn_s_setprio(0);                                    \
            if (sw == 0) op[(size_t)t * 512] = h;                             \
        }                                                                     \
    }

    for (int tt = 0; tt < TS; tt += 4) {
        BODY(0, xs2, xs0)
        BODY(1, xs3, xs1)
        BODY(2, xs0, xs2)
        BODY(3, xs1, xs3)
    }
#undef BODY
#undef PREDUCE
#undef PPROD
#undef XLOAD

    if (role == 0 && sw == 0)
        hout[(g * 32 + b) * 64 + lane] = h;
}

extern "C" void kernel_launch(void* const* d_in, const int* in_sizes, int n_in,
                              void* d_out, int out_size, void* d_ws, size_t ws_size,
                              hipStream_t stream) {
    const float* x  = (const float*)d_in[0];
    const float* h0 = (const float*)d_in[1];
    const float* W  = (const float*)d_in[2];
    const float* U  = (const float*)d_in[3];
    const float* bi = (const float*)d_in[4];
    const float* bh = (const float*)d_in[5];
    float* out  = (float*)d_out;
    float* hout = out + (size_t)32 * TS * 512;
    hipLaunchKernelGGL(gru_fused8, dim3(256), dim3(512), 0, stream,
                       x, h0, W, U, bi, bh, out, hout);
}

// Round 12
// 485.786 us; speedup vs baseline: 1.1307x; 1.0183x over previous
//
#include <hip/hip_runtime.h>

#define TS 1000

__device__ __forceinline__ float rl(float v, int l) {
    return __int_as_float(__builtin_amdgcn_readlane(__float_as_int(v), l));
}
__device__ __forceinline__ float fsig(float x) {
    return __builtin_amdgcn_rcpf(1.0f + __expf(-x));
}
__device__ __forceinline__ float ftanh(float x) {
    return 1.0f - 2.0f * __builtin_amdgcn_rcpf(1.0f + __expf(2.0f * x));
}

// Round-8 structure (best measured: 518 us kernel / 484 total) with two
// surgical deltas:
//   (1) s_setprio REMOVED — m190-style priority inversion: boosting the
//       consumer post-barrier starves the co-SIMD producer, which then
//       arrives late at the next barrier (lockstep kernel = setprio's
//       proven-negative regime).
//   (2) PREDUCE rotated across producer waves (sw == J&3 does step J's
//       pre-reduce) — removes the permanent producer-sw0 straggler
//       (+15 instr every step on one wave).
//
// One block per (g,b) chain, 8 waves (2/SIMD):
//   wid 0-3 = consumers: U·h(t) partials, K-split 16.
//   wid 4-7 = producers: W·x(t+2) partials, K-split 16, x prefetched deep
//             via inline-asm global_load + tied s_waitcnt vmcnt(2).
//   one producer per step PRE-REDUCES the 4 gx partials of step t+1 into
//   psum[(t+1)&3] (producers have issue slack; consumers are critical).
// One NON-draining s_barrier per step; x loads stay in flight across it.
// Ring audit (write pre-barrier, read post-barrier, >=2 barriers between
// last read and rewrite):
//   cpart[t&1]: write pre-b(t), read post-b(t), rewrite pre-b(t+2).
//   ppart[s=(t+2)&3]: write pre-b(t), reducer-read pre-b(t+1), rewrite pre-b(t+4).
//   psum[s=(t+1)&3]: write pre-b(t), consumer-read post-b(t+1),
//                    rewrite pre-b(t+4).
// All 4 consumer waves compute gates redundantly with identical fixed-order
// sums -> bitwise-identical h replicas -> deterministic across replays.
// psum content is wave-independent (same inputs, same expression), so the
// rotation cannot change results.
__global__ __launch_bounds__(512)
__attribute__((amdgpu_waves_per_eu(2, 2)))
void gru_fused8(const float* __restrict__ x, const float* __restrict__ h0,
                const float* __restrict__ W, const float* __restrict__ U,
                const float* __restrict__ bi, const float* __restrict__ bh,
                float* __restrict__ out, float* __restrict__ hout)
{
    __shared__ float4 cpart[2][4][64];   // consumer partials, slot = t & 1
    __shared__ float4 ppart[4][4][64];   // producer partials, slot s holds gx(s mod)
    __shared__ float4 psum[4][64];       // pre-reduced gx, slot = t & 3

    const int tid  = threadIdx.x;
    const int lane = tid & 63;
    const int wid  = tid >> 6;
    const int role = wid >> 2;               // 0 = consumer, 1 = producer
    const int sw   = wid & 3;                // K-split index within role
    const int kb   = __builtin_amdgcn_readfirstlane(sw * 16);

    const int g = blockIdx.x >> 5, b = blockIdx.x & 31;

    // 48 stationary weights/lane: k-rows kb..kb+15, 3 gate columns.
    float w0[16], w1[16], w2[16];
    {
        const float* P = ((role == 0) ? U : W) + (size_t)g * (64 * 192) + (size_t)kb * 192 + lane;
        #pragma unroll
        for (int k = 0; k < 16; ++k) {
            w0[k] = P[k * 192];
            w1[k] = P[k * 192 + 64];
            w2[k] = P[k * 192 + 128];
        }
    }
    #pragma unroll
    for (int k = 0; k < 16; ++k)
        asm volatile("" : "+v"(w0[k]), "+v"(w1[k]), "+v"(w2[k]));

    // b_h folded into consumer sw0; b_i folded into producer sw0.
    float bz = 0.f, br = 0.f, bn = 0.f;
    if (sw == 0) {
        const float* bb = ((role == 0) ? bh : bi) + g * 192 + lane;
        bz = bb[0]; br = bb[64]; bn = bb[128];
    }

    float h = 0.f;
    if (role == 0) h = h0[(g * 32 + b) * 64 + lane];   // replicated, 4 consumer waves

    const float* xp = x + (size_t)b * (TS * 512) + g * 64 + lane;
    float* op = out + (size_t)b * (TS * 512) + g * 64 + lane;

    // Producer x register sets, written ONLY by asm loads, statically indexed
    // via the 4x-unrolled t-loop: set (time & 3) holds x(time).
    float xs0 = 0.f, xs1 = 0.f, xs2 = 0.f, xs3 = 0.f;

#define XLOAD(DST, T_)                                                        \
    { const float* pp_ = xp + (size_t)(T_) * 512;                             \
      asm volatile("global_load_dword %0, %1, off" : "=v"(DST) : "v"(pp_)); }

#define PPROD(XS, SLOT)                                                       \
    {                                                                         \
        float az = bz, ar = br, an = bn;                                      \
        _Pragma("unroll")                                                     \
        for (int k = 0; k < 16; ++k) {                                        \
            const float s = rl(XS, kb + k);                                   \
            az = fmaf(s, w0[k], az);                                          \
            ar = fmaf(s, w1[k], ar);                                          \
            an = fmaf(s, w2[k], an);                                          \
        }                                                                     \
        ppart[SLOT][sw][lane] = make_float4(az, ar, an, 0.f);                 \
    }

#define PREDUCE(SLOT)                                                         \
    {                                                                         \
        const float4 q0 = ppart[SLOT][0][lane];                               \
        const float4 q1 = ppart[SLOT][1][lane];                               \
        const float4 q2 = ppart[SLOT][2][lane];                               \
        const float4 q3 = ppart[SLOT][3][lane];                               \
        psum[SLOT][lane] = make_float4(((q0.x + q1.x) + q2.x) + q3.x,         \
                                       ((q0.y + q1.y) + q2.y) + q3.y,         \
                                       ((q0.z + q1.z) + q2.z) + q3.z, 0.f);   \
    }

    // ---- producer prologue: gx(0)->ppart[0], gx(1)->ppart[1]; x(2),x(3) in flight.
    if (role == 1) {
        XLOAD(xs0, 0) XLOAD(xs1, 1) XLOAD(xs2, 2) XLOAD(xs3, 3)
        asm volatile("s_waitcnt vmcnt(2)" : "+v"(xs0), "+v"(xs1));
        PPROD(xs0, 0)
        PPROD(xs1, 1)
    }
    asm volatile("s_waitcnt lgkmcnt(0)" ::: "memory");
    __builtin_amdgcn_s_barrier();
    // psum[0] = sum of gx(0) partials, pre-b(0); consumer reads it post-b(0).
    // sw3 (not sw0) to balance against sw0's bias-folded PPRODs.
    if (role == 1 && sw == 3) PREDUCE(0)

#define BODY(J, XS_USE, XS_FILL)                                              \
    {                                                                         \
        const int t = tt + (J);                                               \
        if (role == 1) {                                                      \
            /* issue x(t+4) into the set freed 2 bodies ago */                \
            int tl = t + 4; if (tl > TS - 1) tl = TS - 1;                     \
            XLOAD(XS_FILL, tl)                                                \
            /* x(t+2) guaranteed arrived: 3 outstanding -> wait to 2 */       \
            asm volatile("s_waitcnt vmcnt(2)" : "+v"(XS_USE));                \
            PPROD(XS_USE, (J + 2) & 3)                                        \
            if (sw == ((J) & 3)) PREDUCE((J + 1) & 3)  /* rotated reducer */  \
        } else {                                                              \
            float az = bz, ar = br, an = bn;                                  \
            _Pragma("unroll")                                                 \
            for (int k = 0; k < 16; ++k) {                                    \
                const float s = rl(h, kb + k);                                \
                az = fmaf(s, w0[k], az);                                      \
                ar = fmaf(s, w1[k], ar);                                      \
                an = fmaf(s, w2[k], an);                                      \
            }                                                                 \
            cpart[(J) & 1][sw][lane] = make_float4(az, ar, an, 0.f);          \
        }                                                                     \
        asm volatile("s_waitcnt lgkmcnt(0)" ::: "memory");                    \
        __builtin_amdgcn_sched_barrier(0);                                    \
        __builtin_amdgcn_s_barrier();          /* NO vmcnt drain */           \
        __builtin_amdgcn_sched_barrier(0);                                    \
        if (role == 0) {                                                      \
            const float4 c0 = cpart[(J) & 1][0][lane];                        \
            const float4 c1 = cpart[(J) & 1][1][lane];                        \
            const float4 c2 = cpart[(J) & 1][2][lane];                        \
            const float4 c3 = cpart[(J) & 1][3][lane];                        \
            const float4 q  = psum[(J) & 3][lane];                            \
            const float ghz = ((c0.x + c1.x) + c2.x) + c3.x;                  \
            const float ghr = ((c0.y + c1.y) + c2.y) + c3.y;                  \
            const float ghn = ((c0.z + c1.z) + c2.z) + c3.z;                  \
            const float z = fsig(q.x + ghz);                                  \
            const float r = fsig(q.y + ghr);                                  \
            const float n = ftanh(fmaf(r, ghn, q.z));    /* reset_after */    \
            h = n + z * (h - n);                                              \
            if (sw == 0) op[(size_t)t * 512] = h;                             \
        }                                                                     \
    }

    for (int tt = 0; tt < TS; tt += 4) {
        BODY(0, xs2, xs0)
        BODY(1, xs3, xs1)
        BODY(2, xs0, xs2)
        BODY(3, xs1, xs3)
    }
#undef BODY
#undef PREDUCE
#undef PPROD
#undef XLOAD

    if (role == 0 && sw == 0)
        hout[(g * 32 + b) * 64 + lane] = h;
}

extern "C" void kernel_launch(void* const* d_in, const int* in_sizes, int n_in,
                              void* d_out, int out_size, void* d_ws, size_t ws_size,
                              hipStream_t stream) {
    const float* x  = (const float*)d_in[0];
    const float* h0 = (const float*)d_in[1];
    const float* W  = (const float*)d_in[2];
    const float* U  = (const float*)d_in[3];
    const float* bi = (const float*)d_in[4];
    const float* bh = (const float*)d_in[5];
    float* out  = (float*)d_out;
    float* hout = out + (size_t)32 * TS * 512;
    hipLaunchKernelGGL(gru_fused8, dim3(256), dim3(512), 0, stream,
                       x, h0, W, U, bi, bh, out, hout);
}

// Round 13
// 331.723 us; speedup vs baseline: 1.6558x; 1.4644x over previous
//
#include <hip/hip_runtime.h>

#define TS 1000

typedef _Float16 half2v __attribute__((ext_vector_type(2)));

__device__ __forceinline__ float rl(float v, int l) {
    return __int_as_float(__builtin_amdgcn_readlane(__float_as_int(v), l));
}
__device__ __forceinline__ int rli(int v, int l) {
    return __builtin_amdgcn_readlane(v, l);
}
__device__ __forceinline__ float fsig(float x) {
    return __builtin_amdgcn_rcpf(1.0f + __expf(-x));
}
__device__ __forceinline__ float ftanh(float x) {
    return 1.0f - 2.0f * __builtin_amdgcn_rcpf(1.0f + __expf(2.0f * x));
}

// One block per (g,b) chain, 8 waves, barrier once per 4-step WINDOW:
//   w0 = THE consumer: full U·h matvec per step as 96 v_dot2_f32_f16
//        (U packed as 96 half2 regs; h-pair packed per step via DPP xor-1
//        + cvt_f16). No per-step exchange, no h replicas. Alone on SIMD0.
//   w1,w2,w3,w5 = producers: W·x partials K-split 16 (f32, exact gx),
//        one window (4 steps) ahead; rotating per-step psum pre-reduce.
//   w4,w6,w7 idle (barrier participants only).
// Windows: during window w (parity P=w&1):
//   consumer: steps [4w,4w+4) reading psum[P] (written during w-1).
//   producers: PPROD steps [4w+8,4w+12) -> ppart[P] (x loaded during w-1,
//              counted vmcnt(4)); PREDUCE psum[P^1] (steps [4w+4,4w+8))
//              from ppart[P^1] (written during w-1).
// Ring audit: every slot has >=1 barrier between write & read and between
// read & rewrite (ppart[P^1]: read@w, rewritten@w+1; psum[P^1]: written@w,
// read@w+1, rewritten@w+2). One s_barrier per window, non-draining; x loads
// in flight across it. Single h owner -> deterministic across replays.
__global__ __launch_bounds__(512)
__attribute__((amdgpu_waves_per_eu(2, 2)))
void gru_win(const float* __restrict__ x, const float* __restrict__ h0,
             const float* __restrict__ W, const float* __restrict__ U,
             const float* __restrict__ bi, const float* __restrict__ bh,
             float* __restrict__ out, float* __restrict__ hout)
{
    __shared__ float4 ppart[2][4][4][64];   // [slot][step j][ksplit][lane]
    __shared__ float4 psum[2][4][64];       // [slot][step j][lane]

    const int tid  = threadIdx.x;
    const int lane = tid & 63;
    const int wid  = tid >> 6;
    const bool cons = (wid == 0);
    const bool prod = (wid == 1) || (wid == 2) || (wid == 3) || (wid == 5);
    const int sw   = (wid == 5) ? 3 : (wid - 1);            // producer K-index
    const int kb   = __builtin_amdgcn_readfirstlane(prod ? sw * 16 : 0);

    const int g = blockIdx.x >> 5, b = blockIdx.x & 31;

    // ---------------- consumer state: 96 packed half2 U-weights + h + bias
    int uw[96];                      // [gate*32 + k2] = half2(U[2k2], U[2k2+1])
    float h = 0.f, bhz = 0.f, bhr = 0.f, bhn = 0.f;
    float* op = out + (size_t)b * (TS * 512) + g * 64 + lane;
    if (cons) {
        const float* Ug = U + (size_t)g * (64 * 192) + lane;
        #pragma unroll
        for (int k2 = 0; k2 < 32; ++k2) {
            #pragma unroll
            for (int gate = 0; gate < 3; ++gate) {
                const float a = Ug[(2 * k2) * 192 + gate * 64];
                const float c = Ug[(2 * k2 + 1) * 192 + gate * 64];
                half2v p; p.x = (_Float16)a; p.y = (_Float16)c;   // RNE cvt
                uw[gate * 32 + k2] = __builtin_bit_cast(int, p);
            }
        }
        #pragma unroll
        for (int k2 = 0; k2 < 32; ++k2)
            asm volatile("" : "+v"(uw[k2]), "+v"(uw[32 + k2]), "+v"(uw[64 + k2]));
        bhz = bh[g * 192 + lane];
        bhr = bh[g * 192 + 64 + lane];
        bhn = bh[g * 192 + 128 + lane];
        h   = h0[(g * 32 + b) * 64 + lane];
    }

    // ---------------- producer state: 48 f32 W-weights + x batch regs
    float w0[16], w1[16], w2[16];
    float bz = 0.f, br = 0.f, bn = 0.f;
    const float* xp = x + (size_t)b * (TS * 512) + g * 64 + lane;
    float xa0 = 0, xa1 = 0, xa2 = 0, xa3 = 0, xb0 = 0, xb1 = 0, xb2 = 0, xb3 = 0;
    if (prod) {
        const float* Wg = W + (size_t)g * (64 * 192) + (size_t)kb * 192 + lane;
        #pragma unroll
        for (int k = 0; k < 16; ++k) {
            w0[k] = Wg[k * 192];
            w1[k] = Wg[k * 192 + 64];
            w2[k] = Wg[k * 192 + 128];
        }
        #pragma unroll
        for (int k = 0; k < 16; ++k)
            asm volatile("" : "+v"(w0[k]), "+v"(w1[k]), "+v"(w2[k]));
        if (sw == 0) {
            bz = bi[g * 192 + lane];
            br = bi[g * 192 + 64 + lane];
            bn = bi[g * 192 + 128 + lane];
        }
    }

#define XLOAD(DST, T_)                                                        \
    { const float* pp_ = xp + (size_t)(T_) * 512;                             \
      asm volatile("global_load_dword %0, %1, off" : "=v"(DST) : "v"(pp_)); }

#define PPROD(XS, SLOT, J)                                                    \
    {                                                                         \
        float az = bz, ar = br, an = bn, az2 = 0.f, ar2 = 0.f, an2 = 0.f;     \
        _Pragma("unroll")                                                     \
        for (int k = 0; k < 8; ++k) {                                         \
            const float s = rl(XS, kb + k);                                   \
            az = fmaf(s, w0[k], az); ar = fmaf(s, w1[k], ar); an = fmaf(s, w2[k], an); \
        }                                                                     \
        _Pragma("unroll")                                                     \
        for (int k = 8; k < 16; ++k) {                                        \
            const float s = rl(XS, kb + k);                                   \
            az2 = fmaf(s, w0[k], az2); ar2 = fmaf(s, w1[k], ar2); an2 = fmaf(s, w2[k], an2); \
        }                                                                     \
        ppart[SLOT][J][sw][lane] = make_float4(az + az2, ar + ar2, an + an2, 0.f); \
    }

#define PREDUCE(SLOT)                                                         \
    {                                                                         \
        const float4 q0 = ppart[SLOT][sw][0][lane];                           \
        const float4 q1 = ppart[SLOT][sw][1][lane];                           \
        const float4 q2 = ppart[SLOT][sw][2][lane];                           \
        const float4 q3 = ppart[SLOT][sw][3][lane];                           \
        psum[SLOT][sw][lane] = make_float4(((q0.x + q1.x) + q2.x) + q3.x,     \
                                           ((q0.y + q1.y) + q2.y) + q3.y,     \
                                           ((q0.z + q1.z) + q2.z) + q3.z, 0.f); \
    }

#define CSTEP(P, J)                                                           \
    {                                                                         \
        const float4 q = psum[P][J][lane];                                    \
        const int hxi = __builtin_amdgcn_update_dpp(                          \
            0, __float_as_int(h), 0xB1 /*quad_perm(1,0,3,2)*/, 0xF, 0xF, true); \
        half2v hp; hp.x = (_Float16)h; hp.y = (_Float16)__int_as_float(hxi);  \
        const int hpi = __builtin_bit_cast(int, hp);                          \
        float az = bhz, ar = bhr, an = bhn, az2 = 0.f, ar2 = 0.f, an2 = 0.f;  \
        _Pragma("unroll")                                                     \
        for (int k2 = 0; k2 < 16; ++k2) {                                     \
            const half2v hv = __builtin_bit_cast(half2v, rli(hpi, 2 * k2));   \
            az = __builtin_amdgcn_fdot2(__builtin_bit_cast(half2v, uw[k2]),      hv, az, false); \
            ar = __builtin_amdgcn_fdot2(__builtin_bit_cast(half2v, uw[32 + k2]), hv, ar, false); \
            an = __builtin_amdgcn_fdot2(__builtin_bit_cast(half2v, uw[64 + k2]), hv, an, false); \
        }                                                                     \
        _Pragma("unroll")                                                     \
        for (int k2 = 16; k2 < 32; ++k2) {                                    \
            const half2v hv = __builtin_bit_cast(half2v, rli(hpi, 2 * k2));   \
            az2 = __builtin_amdgcn_fdot2(__builtin_bit_cast(half2v, uw[k2]),      hv, az2, false); \
            ar2 = __builtin_amdgcn_fdot2(__builtin_bit_cast(half2v, uw[32 + k2]), hv, ar2, false); \
            an2 = __builtin_amdgcn_fdot2(__builtin_bit_cast(half2v, uw[64 + k2]), hv, an2, false); \
        }                                                                     \
        const float z = fsig(q.x + (az + az2));                               \
        const float r = fsig(q.y + (ar + ar2));                               \
        const float n = ftanh(fmaf(r, (an + an2), q.z));   /* reset_after */  \
        h = n + z * (h - n);                                                  \
        op[0] = h; op += 512;                                                 \
    }

    // ---------------- prologue: partials for steps 0-7; x[8..12) in flight.
    if (prod) {
        XLOAD(xa0, 0) XLOAD(xa1, 1) XLOAD(xa2, 2) XLOAD(xa3, 3)
        XLOAD(xb0, 4) XLOAD(xb1, 5) XLOAD(xb2, 6) XLOAD(xb3, 7)
        asm volatile("s_waitcnt vmcnt(0)"
                     : "+v"(xa0), "+v"(xa1), "+v"(xa2), "+v"(xa3),
                       "+v"(xb0), "+v"(xb1), "+v"(xb2), "+v"(xb3));
        PPROD(xa0, 0, 0) PPROD(xa1, 0, 1) PPROD(xa2, 0, 2) PPROD(xa3, 0, 3)
        PPROD(xb0, 1, 0) PPROD(xb1, 1, 1) PPROD(xb2, 1, 2) PPROD(xb3, 1, 3)
        XLOAD(xa0, 8) XLOAD(xa1, 9) XLOAD(xa2, 10) XLOAD(xa3, 11)
    }
    asm volatile("s_waitcnt lgkmcnt(0)" ::: "memory");
    __builtin_amdgcn_s_barrier();
    if (prod) PREDUCE(0)                       // psum[0] = steps 0-3
    asm volatile("s_waitcnt lgkmcnt(0)" ::: "memory");
    __builtin_amdgcn_s_barrier();

#define WINDOW(P, XU0, XU1, XU2, XU3, XF0, XF1, XF2, XF3)                     \
    {                                                                         \
        const int t0 = (dw * 2 + (P)) * 4;                                    \
        if (prod) {                                                           \
            int tl;                                                           \
            tl = t0 + 12; if (tl > TS - 1) tl = TS - 1; XLOAD(XF0, tl)        \
            tl = t0 + 13; if (tl > TS - 1) tl = TS - 1; XLOAD(XF1, tl)        \
            tl = t0 + 14; if (tl > TS - 1) tl = TS - 1; XLOAD(XF2, tl)        \
            tl = t0 + 15; if (tl > TS - 1) tl = TS - 1; XLOAD(XF3, tl)        \
            asm volatile("s_waitcnt vmcnt(4)"                                 \
                         : "+v"(XU0), "+v"(XU1), "+v"(XU2), "+v"(XU3));       \
            PPROD(XU0, P, 0) PPROD(XU1, P, 1) PPROD(XU2, P, 2) PPROD(XU3, P, 3) \
            PREDUCE((P) ^ 1)                                                  \
        }                                                                     \
        if (cons) {                                                           \
            CSTEP(P, 0) CSTEP(P, 1) CSTEP(P, 2) CSTEP(P, 3)                   \
        }                                                                     \
        asm volatile("s_waitcnt lgkmcnt(0)" ::: "memory");                    \
        __builtin_amdgcn_sched_barrier(0);                                    \
        __builtin_amdgcn_s_barrier();          /* NO vmcnt drain */           \
        __builtin_amdgcn_sched_barrier(0);                                    \
    }

    for (int dw = 0; dw < 125; ++dw) {
        WINDOW(0, xa0, xa1, xa2, xa3, xb0, xb1, xb2, xb3)
        WINDOW(1, xb0, xb1, xb2, xb3, xa0, xa1, xa2, xa3)
    }
#undef WINDOW
#undef CSTEP
#undef PREDUCE
#undef PPROD
#undef XLOAD

    if (cons)
        hout[(g * 32 + b) * 64 + lane] = h;
}

extern "C" void kernel_launch(void* const* d_in, const int* in_sizes, int n_in,
                              void* d_out, int out_size, void* d_ws, size_t ws_size,
                              hipStream_t stream) {
    const float* x  = (const float*)d_in[0];
    const float* h0 = (const float*)d_in[1];
    const float* W  = (const float*)d_in[2];
    const float* U  = (const float*)d_in[3];
    const float* bi = (const float*)d_in[4];
    const float* bh = (const float*)d_in[5];
    float* out  = (float*)d_out;
    float* hout = out + (size_t)32 * TS * 512;
    hipLaunchKernelGGL(gru_win, dim3(256), dim3(512), 0, stream,
                       x, h0, W, U, bi, bh, out, hout);
}

// Round 14
// 318.574 us; speedup vs baseline: 1.7241x; 1.0413x over previous
//
#include <hip/hip_runtime.h>

#define TS 1000

typedef _Float16 half2v __attribute__((ext_vector_type(2)));

__device__ __forceinline__ int rli(int v, int l) {
    return __builtin_amdgcn_readlane(v, l);
}
__device__ __forceinline__ float fsig(float x) {
    return __builtin_amdgcn_rcpf(1.0f + __expf(-x));
}
__device__ __forceinline__ float ftanh(float x) {
    return 1.0f - 2.0f * __builtin_amdgcn_rcpf(1.0f + __expf(2.0f * x));
}

// One block per (g,b) chain, 8 waves, ONE code shape for all roles:
//   every active wave holds 96 packed-half2 weight dwords (w0: U-f16,
//   others: W-f16) and runs the SAME 32-readlane + 96-dot2 matvec.
//   -> register live-set is identical across waves (~118), so the RA
//   stops spilling (round 13: union of two different 170-reg shapes
//   was granted only 104 -> ~60 spilled regs of AGPR/scratch traffic).
//   w0          = consumer: U·h(t) + gates + h-update (sole h owner).
//   w1,w2,w3,w5 = producers: producer j computes the FULL gx(step) for
//                 step 4(w+2)+j alone (f16 dot2, f32 accum + f32 bias),
//                 writes psum[(w+2)&3][j] directly. No K-split, no
//                 ppart, no PREDUCE.
//   w4,w6,w7    = barrier participants only (keep consumer alone on SIMD0).
// One NON-draining s_barrier per 4-step window; x loads in flight across it
// (2-deep per producer, tied s_waitcnt vmcnt(1)).
// psum ring audit (single writer per slot): slot s=(w+2)&3 written
// pre-b(w), read by consumer during w+2 (after b(w), b(w+1)), rewritten
// pre-b(w+4) (after the read's barrier b(w+2)). >=1 barrier both ways.
// Single h owner -> bitwise deterministic across graph replays.
__global__ __launch_bounds__(512)
__attribute__((amdgpu_waves_per_eu(2, 2)))
void gru_uni(const float* __restrict__ x, const float* __restrict__ h0,
             const float* __restrict__ W, const float* __restrict__ U,
             const float* __restrict__ bi, const float* __restrict__ bh,
             float* __restrict__ out, float* __restrict__ hout)
{
    __shared__ float4 psum[4][4][64];    // [slot][step j][lane], 16 KB

    const int tid  = threadIdx.x;
    const int lane = tid & 63;
    const int wid  = tid >> 6;
    const bool cons = (wid == 0);
    const bool prod = (wid == 1) | (wid == 2) | (wid == 3) | (wid == 5);
    const int jmap = (wid == 5) ? 3 : (wid - 1);     // producer step index

    const int g = blockIdx.x >> 5, b = blockIdx.x & 31;

    // ---- unified weight pack: 96 half2 dwords/lane. w0 packs U, all
    // others pack W (idle waves too — keeps one load site, one reg shape).
    int uw[96];                  // [gate*32 + k2] = half2(M[2k2], M[2k2+1])
    {
        const float* Pg = (cons ? U : W) + (size_t)g * (64 * 192) + lane;
        #pragma unroll
        for (int k2 = 0; k2 < 32; ++k2) {
            #pragma unroll
            for (int gate = 0; gate < 3; ++gate) {
                const float a = Pg[(2 * k2) * 192 + gate * 64];
                const float c = Pg[(2 * k2 + 1) * 192 + gate * 64];
                half2v p; p.x = (_Float16)a; p.y = (_Float16)c;   // RNE
                uw[gate * 32 + k2] = __builtin_bit_cast(int, p);
            }
        }
    }
    #pragma unroll
    for (int k2 = 0; k2 < 32; ++k2)
        asm volatile("" : "+v"(uw[k2]), "+v"(uw[32 + k2]), "+v"(uw[64 + k2]));

    // f32 biases: consumer = b_h, producers = b_i (accumulator init).
    float b0 = 0.f, b1 = 0.f, b2 = 0.f;
    {
        const float* bb = (cons ? bh : bi) + g * 192 + lane;
        b0 = bb[0]; b1 = bb[64]; b2 = bb[128];
    }

    float h = 0.f;
    if (cons) h = h0[(g * 32 + b) * 64 + lane];

    const float* xp = x + (size_t)b * (TS * 512) + g * 64 + lane;
    float* op = out + (size_t)b * (TS * 512) + g * 64 + lane;

// pack src pair via DPP xor-1 lane swap, then 32 readlane + 96 dot2 (f32 acc)
#define MATVEC(SRCV, OZ, OR, ON)                                              \
    {                                                                         \
        const int sxi_ = __builtin_amdgcn_update_dpp(                         \
            0, __float_as_int(SRCV), 0xB1, 0xF, 0xF, true);                   \
        half2v sp_; sp_.x = (_Float16)(SRCV);                                 \
        sp_.y = (_Float16)__int_as_float(sxi_);                               \
        const int spi_ = __builtin_bit_cast(int, sp_);                        \
        float _az = b0, _ar = b1, _an = b2, _az2 = 0.f, _ar2 = 0.f, _an2 = 0.f; \
        _Pragma("unroll")                                                     \
        for (int k2 = 0; k2 < 16; ++k2) {                                     \
            const half2v hv_ = __builtin_bit_cast(half2v, rli(spi_, 2 * k2)); \
            _az = __builtin_amdgcn_fdot2(__builtin_bit_cast(half2v, uw[k2]),      hv_, _az, false); \
            _ar = __builtin_amdgcn_fdot2(__builtin_bit_cast(half2v, uw[32 + k2]), hv_, _ar, false); \
            _an = __builtin_amdgcn_fdot2(__builtin_bit_cast(half2v, uw[64 + k2]), hv_, _an, false); \
        }                                                                     \
        _Pragma("unroll")                                                     \
        for (int k2 = 16; k2 < 32; ++k2) {                                    \
            const half2v hv_ = __builtin_bit_cast(half2v, rli(spi_, 2 * k2)); \
            _az2 = __builtin_amdgcn_fdot2(__builtin_bit_cast(half2v, uw[k2]),      hv_, _az2, false); \
            _ar2 = __builtin_amdgcn_fdot2(__builtin_bit_cast(half2v, uw[32 + k2]), hv_, _ar2, false); \
            _an2 = __builtin_amdgcn_fdot2(__builtin_bit_cast(half2v, uw[64 + k2]), hv_, _an2, false); \
        }                                                                     \
        OZ = _az + _az2; OR = _ar + _ar2; ON = _an + _an2;                    \
    }

#define XLOAD(DST, T_)                                                        \
    { const float* pp_ = xp + (size_t)(T_) * 512;                             \
      asm volatile("global_load_dword %0, %1, off" : "=v"(DST) : "v"(pp_)); }

#define PSTEP(XS, WR)                                                         \
    {                                                                         \
        float pz_, pr_, pn_;                                                  \
        MATVEC(XS, pz_, pr_, pn_)                                             \
        psum[WR][jmap][lane] = make_float4(pz_, pr_, pn_, 0.f);               \
    }

#define CSTEP(RD, J)                                                          \
    {                                                                         \
        const float4 q = psum[RD][J][lane];                                   \
        float ghz, ghr, ghn;                                                  \
        MATVEC(h, ghz, ghr, ghn)                                              \
        const float z = fsig(q.x + ghz);                                      \
        const float r = fsig(q.y + ghr);                                      \
        const float n = ftanh(fmaf(r, ghn, q.z));   /* reset_after */         \
        h = n + z * (h - n);                                                  \
        op[0] = h; op += 512;                                                 \
    }

    // ---- prologue: psum[0] (steps 0-3), psum[1] (steps 4-7); x(8+j) in flight.
    float xa = 0.f, xb = 0.f;
    if (prod) {
        XLOAD(xa, jmap) XLOAD(xb, 4 + jmap)
        asm volatile("s_waitcnt vmcnt(0)" : "+v"(xa), "+v"(xb));
        PSTEP(xa, 0)
        PSTEP(xb, 1)
        XLOAD(xa, 8 + jmap)
    }
    asm volatile("s_waitcnt lgkmcnt(0)" ::: "memory");
    __builtin_amdgcn_s_barrier();

#define WINDOW(P, XU, XF)                                                     \
    {                                                                         \
        const int w  = dw * 2 + (P);                                          \
        const int rd = w & 3;                                                 \
        const int wr = (w + 2) & 3;                                           \
        if (cons) {                                                           \
            CSTEP(rd, 0) CSTEP(rd, 1) CSTEP(rd, 2) CSTEP(rd, 3)               \
        } else if (prod) {                                                    \
            int tl = 4 * (w + 3) + jmap; if (tl > TS - 1) tl = TS - 1;        \
            XLOAD(XF, tl)                                                     \
            asm volatile("s_waitcnt vmcnt(1)" : "+v"(XU));                    \
            PSTEP(XU, wr)                                                     \
        }                                                                     \
        asm volatile("s_waitcnt lgkmcnt(0)" ::: "memory");                    \
        __builtin_amdgcn_sched_barrier(0);                                    \
        __builtin_amdgcn_s_barrier();          /* NO vmcnt drain */           \
        __builtin_amdgcn_sched_barrier(0);                                    \
    }

    for (int dw = 0; dw < 125; ++dw) {
        WINDOW(0, xa, xb)
        WINDOW(1, xb, xa)
    }
#undef WINDOW
#undef CSTEP
#undef PSTEP
#undef XLOAD
#undef MATVEC

    if (cons)
        hout[(g * 32 + b) * 64 + lane] = h;
}

extern "C" void kernel_launch(void* const* d_in, const int* in_sizes, int n_in,
                              void* d_out, int out_size, void* d_ws, size_t ws_size,
                              hipStream_t stream) {
    const float* x  = (const float*)d_in[0];
    const float* h0 = (const float*)d_in[1];
    const float* W  = (const float*)d_in[2];
    const float* U  = (const float*)d_in[3];
    const float* bi = (const float*)d_in[4];
    const float* bh = (const float*)d_in[5];
    float* out  = (float*)d_out;
    float* hout = out + (size_t)32 * TS * 512;
    hipLaunchKernelGGL(gru_uni, dim3(256), dim3(512), 0, stream,
                       x, h0, W, U, bi, bh, out, hout);
}